// Round 4
// baseline (3510.955 us; speedup 1.0000x reference)
//
#include <hip/hip_runtime.h>
#include <cmath>

constexpr int NFEAT = 1024;
constexpr int HID   = 64;
constexpr int NC    = 16;
constexpr int EB    = 8192;   // edges per k_bin block

typedef __attribute__((ext_vector_type(8))) short bf16x8;
typedef __attribute__((ext_vector_type(4))) float f32x4;
typedef __attribute__((ext_vector_type(8))) unsigned short u16x8;

__device__ inline unsigned short f2bf(float f) {
  unsigned u = __float_as_uint(f);
  unsigned r = u + 0x7FFFu + ((u >> 16) & 1u);
  return (unsigned short)(r >> 16);
}
__device__ inline float bflo(unsigned u) { return __uint_as_float(u << 16); }
__device__ inline float bfhi(unsigned u) { return __uint_as_float(u & 0xFFFF0000u); }

// ---------------- bucket cursor init: bc[i] = i*cap ----------------
__global__ __launch_bounds__(256) void k_bcinit(int* __restrict__ bc1, int* __restrict__ bc2,
                                                int nb, int cap1, int cap2) {
  int i = blockIdx.x * 256 + threadIdx.x;
  if (i < nb) { bc1[i] = i * cap1; bc2[i] = i * cap2; }
}

// ---------------- bin edges into 64-row buckets (fixed-capacity, packed words) ----------------
// packed = (row & 63) << 17 | col   (requires n <= 131072)
__global__ __launch_bounds__(256) void k_bin(const int* __restrict__ rows, const int* __restrict__ cols,
                                             int* __restrict__ bcur, unsigned* __restrict__ stg,
                                             int e, int nb, int cap) {
  __shared__ int hist[2048];
  __shared__ int cur[2048];
  int t = threadIdx.x;
  for (int i = t; i < nb; i += 256) hist[i] = 0;
  __syncthreads();
  int e0 = blockIdx.x * EB;
  int lim = min(e - e0, EB);
  for (int k = t; k < lim; k += 256)
    atomicAdd(&hist[rows[e0 + k] >> 6], 1);
  __syncthreads();
  for (int i = t; i < nb; i += 256) {
    int c = hist[i];
    cur[i] = c ? atomicAdd(&bcur[i], c) : 0;
  }
  __syncthreads();
  for (int k = t; k < lim; k += 256) {
    int r = rows[e0 + k], c = cols[e0 + k];
    int b = r >> 6;
    int p = atomicAdd(&cur[b], 1);
    if (p < (b + 1) * cap)
      stg[p] = ((unsigned)(r & 63) << 17) | (unsigned)c;
  }
}

// ---------------- per-bucket degree hist -> d = deg^-1/2 ----------------
__global__ __launch_bounds__(256) void k_deg(const unsigned* __restrict__ stg, const int* __restrict__ bc,
                                             int cap, float* __restrict__ d, int n) {
  __shared__ int cnt[64];
  int b = blockIdx.x, t = threadIdx.x;
  int start = b * cap;
  int end = min(bc[b], start + cap);
  if (t < 64) cnt[t] = 0;
  __syncthreads();
  for (int i = start + t; i < end; i += 256)
    atomicAdd(&cnt[stg[i] >> 17], 1);
  __syncthreads();
  int row = b * 64 + t;
  if (t < 64 && row < n)
    d[row] = (cnt[t] > 0) ? 1.0f / sqrtf((float)cnt[t]) : 0.0f;
}

// ---------------- fused embed GEMM (bf16 MFMA) + 112-wide projection + d-prescale ----------------
// T: t0,t1,t2 f32 [n*16] each (contiguous). U1,U2: bf16 [n*32], prescaled by d1/d2.
__global__ __launch_bounds__(256) void k_embed(const float* __restrict__ x, const float* __restrict__ we,
                                               const float* __restrict__ wcl,
                                               const float* __restrict__ d1, const float* __restrict__ d2,
                                               float* __restrict__ T,
                                               unsigned short* __restrict__ U1, unsigned short* __restrict__ U2,
                                               int n) {
  __shared__ float pool[7168];          // phase1: xs bf16[64][72] + wsb bf16[64][72]; phase2: wall f32[64][112]
  __shared__ float rs[64 * 68];
  unsigned short* xs  = (unsigned short*)pool;           // A tile, [row][k] bf16, stride 72
  unsigned short* wsb = (unsigned short*)(pool + 2304);  // B tile transposed, [n][k] bf16, stride 72

  const int t    = threadIdx.x;
  const int w    = t >> 6;        // wave 0..3
  const int l    = t & 63;
  const int quad = l >> 4;
  const int lr   = l & 15;
  const int br   = blockIdx.x * 64;

  const int sxr = t >> 2;
  const int sxc = (t & 3) * 4;
  const int xrow = min(br + sxr, n - 1);
  const float* xp = x + (size_t)xrow * NFEAT;
  const int swn = t & 63;
  const int swk = (t >> 6) * 4;

  f32x4 acc[4];
#pragma unroll
  for (int i = 0; i < 4; ++i) acc[i] = (f32x4){0.f, 0.f, 0.f, 0.f};

  for (int kc = 0; kc < NFEAT; kc += 64) {
    float4 xv[4];
#pragma unroll
    for (int j = 0; j < 4; ++j) xv[j] = *(const float4*)(xp + kc + j * 16 + sxc);
    float wv[16];
#pragma unroll
    for (int p = 0; p < 4; ++p)
#pragma unroll
      for (int i = 0; i < 4; ++i)
        wv[p * 4 + i] = we[(size_t)(kc + p * 16 + swk + i) * HID + swn];
    __syncthreads();
#pragma unroll
    for (int j = 0; j < 4; ++j) {
      ushort4 u;
      u.x = f2bf(xv[j].x); u.y = f2bf(xv[j].y); u.z = f2bf(xv[j].z); u.w = f2bf(xv[j].w);
      *(ushort4*)&xs[sxr * 72 + j * 16 + sxc] = u;
    }
#pragma unroll
    for (int p = 0; p < 4; ++p) {
      ushort4 u;
      u.x = f2bf(wv[p * 4 + 0]); u.y = f2bf(wv[p * 4 + 1]);
      u.z = f2bf(wv[p * 4 + 2]); u.w = f2bf(wv[p * 4 + 3]);
      *(ushort4*)&wsb[swn * 72 + p * 16 + swk] = u;
    }
    __syncthreads();
#pragma unroll
    for (int ks = 0; ks < 2; ++ks) {
      bf16x8 af = *(const bf16x8*)&xs[(w * 16 + lr) * 72 + ks * 32 + quad * 8];
#pragma unroll
      for (int nt = 0; nt < 4; ++nt) {
        bf16x8 bfr = *(const bf16x8*)&wsb[(nt * 16 + lr) * 72 + ks * 32 + quad * 8];
        acc[nt] = __builtin_amdgcn_mfma_f32_16x16x32_bf16(af, bfr, acc[nt], 0, 0, 0);
      }
    }
  }
  __syncthreads();

#pragma unroll
  for (int nt = 0; nt < 4; ++nt)
#pragma unroll
    for (int r = 0; r < 4; ++r)
      rs[(w * 16 + quad * 4 + r) * 68 + nt * 16 + lr] = fmaxf(acc[nt][r], 0.f);

  // wall load, permuted block order [t0 t1 t2 t3 t5 t4 t6]
  const int srcblk[7] = {0, 1, 2, 3, 5, 4, 6};
  for (int i = t; i < 7168; i += 256) {
    int k = i / 112, c = i % 112;
    int p = c >> 4, cc = c & 15;
    pool[i] = wcl[(size_t)(64 * srcblk[p] + k) * NC + cc];
  }
  __syncthreads();

  const int prow = t >> 2, pcg = t & 3;
  float4 ap[7];
#pragma unroll
  for (int j = 0; j < 7; ++j) ap[j] = make_float4(0.f, 0.f, 0.f, 0.f);
  for (int k = 0; k < 64; ++k) {
    float rv = rs[prow * 68 + k];
#pragma unroll
    for (int j = 0; j < 7; ++j) {
      float4 w4 = *(const float4*)&pool[k * 112 + pcg * 28 + j * 4];
      ap[j].x += rv * w4.x; ap[j].y += rv * w4.y; ap[j].z += rv * w4.z; ap[j].w += rv * w4.w;
    }
  }
  int gr = br + prow;
  if (gr < n) {
    size_t sn = (size_t)n;
    float d1v = d1[gr], d2v = d2[gr];
#pragma unroll
    for (int j = 0; j < 7; ++j) {
      int c = pcg * 28 + j * 4;
      int pb = c >> 4, cc = c & 15;
      float4 v = ap[j];
      if (pb < 3) {
        size_t o = (size_t)pb * 16 * sn + (size_t)gr * 16 + cc;
        *(float4*)(T + o) = v;
      } else {
        float s = (pb < 5) ? d1v : d2v;
        v.x *= s; v.y *= s; v.z *= s; v.w *= s;
        ushort4 u;
        u.x = f2bf(v.x); u.y = f2bf(v.y); u.z = f2bf(v.z); u.w = f2bf(v.w);
        unsigned short* Ub = (pb < 5) ? U1 : U2;
        int half = (pb == 4 || pb == 6) ? 16 : 0;
        *(ushort4*)(Ub + (size_t)gr * 32 + half + cc) = u;
      }
    }
  }
}

// ---------------- fused inner passes + combine: edge-parallel, LDS accumulate ----------------
// block = one 64-row bucket; acc1 = sum_{A1} U1[c], acc2 = sum_{A2} U2[c] (32-wide each)
// p = d1*(t1 + d1*acc1.lo + d2*acc2.lo); q = d2*(t2 + d1*acc1.hi + d2*acc2.hi)   (bf16)
__global__ __launch_bounds__(256) void k_inner(const unsigned* __restrict__ stg1, const int* __restrict__ bc1, int cap1,
                                               const unsigned* __restrict__ stg2, const int* __restrict__ bc2, int cap2,
                                               const float* __restrict__ d1, const float* __restrict__ d2,
                                               const unsigned short* __restrict__ U1,
                                               const unsigned short* __restrict__ U2,
                                               const float* __restrict__ t1, const float* __restrict__ t2,
                                               unsigned short* __restrict__ p, unsigned short* __restrict__ q,
                                               int n) {
  __shared__ float acc1[64 * 33];    // stride 33: bank = (ro + s*8 + k) % 32, spread by ro
  __shared__ float acc2[64 * 33];
  int b = blockIdx.x, t = threadIdx.x;
  for (int i = t; i < 64 * 33; i += 256) { acc1[i] = 0.f; acc2[i] = 0.f; }
  __syncthreads();
  const int g = t >> 2, s = t & 3;

#pragma unroll 1
  for (int pass = 0; pass < 2; ++pass) {
    const unsigned* stg = pass ? stg2 : stg1;
    const int cap = pass ? cap2 : cap1;
    const int endc = pass ? bc2[b] : bc1[b];
    const unsigned short* U = pass ? U2 : U1;
    float* acc = pass ? acc2 : acc1;
    int start = b * cap;
    int cnt = min(endc, start + cap) - start;
    int i = g * 4;
    for (; i + 4 <= cnt; i += 256) {
      uint4 w = *(const uint4*)(stg + start + i);
      unsigned ws[4] = {w.x, w.y, w.z, w.w};
      uint4 v[4];
#pragma unroll
      for (int j = 0; j < 4; ++j)
        v[j] = *(const uint4*)(U + (size_t)(ws[j] & 0x1FFFFu) * 32 + s * 8);
#pragma unroll
      for (int j = 0; j < 4; ++j) {
        float* a = &acc[(ws[j] >> 17) * 33 + s * 8];
        atomicAdd(&a[0], bflo(v[j].x)); atomicAdd(&a[1], bfhi(v[j].x));
        atomicAdd(&a[2], bflo(v[j].y)); atomicAdd(&a[3], bfhi(v[j].y));
        atomicAdd(&a[4], bflo(v[j].z)); atomicAdd(&a[5], bfhi(v[j].z));
        atomicAdd(&a[6], bflo(v[j].w)); atomicAdd(&a[7], bfhi(v[j].w));
      }
    }
    for (int jj = i; jj < cnt; ++jj) {
      unsigned w = stg[start + jj];
      uint4 v = *(const uint4*)(U + (size_t)(w & 0x1FFFFu) * 32 + s * 8);
      float* a = &acc[(w >> 17) * 33 + s * 8];
      atomicAdd(&a[0], bflo(v.x)); atomicAdd(&a[1], bfhi(v.x));
      atomicAdd(&a[2], bflo(v.y)); atomicAdd(&a[3], bfhi(v.y));
      atomicAdd(&a[4], bflo(v.z)); atomicAdd(&a[5], bfhi(v.z));
      atomicAdd(&a[6], bflo(v.w)); atomicAdd(&a[7], bfhi(v.w));
    }
  }
  __syncthreads();

  // finalize: thread -> row g (0..63), slice s
  int row_g = b * 64 + g;
  if (row_g < n) {
    float s1 = d1[row_g], s2 = d2[row_g];
    const float* tb = (s < 2) ? (t1 + (size_t)row_g * 16 + s * 8)
                              : (t2 + (size_t)row_g * 16 + (s - 2) * 8);
    unsigned short* dst = (s < 2) ? (p + (size_t)row_g * 16 + s * 8)
                                  : (q + (size_t)row_g * 16 + (s - 2) * 8);
    float so = (s < 2) ? s1 : s2;
    float4 b0 = *(const float4*)tb;
    float4 b1 = *(const float4*)(tb + 4);
    float bb[8] = {b0.x, b0.y, b0.z, b0.w, b1.x, b1.y, b1.z, b1.w};
    u16x8 us;
#pragma unroll
    for (int i = 0; i < 8; ++i) {
      float v = so * (bb[i] + s1 * acc1[g * 33 + s * 8 + i] + s2 * acc2[g * 33 + s * 8 + i]);
      us[i] = f2bf(v);
    }
    *(u16x8*)dst = us;
  }
}

// ---------------- fused outer passes + log_softmax: edge-parallel, LDS accumulate ----------------
// accA = sum_{A1} p[c], accB = sum_{A2} q[c]; z = t0 + d1*accA + d2*accB; out = log_softmax(z)
__global__ __launch_bounds__(256) void k_outer(const unsigned* __restrict__ stg1, const int* __restrict__ bc1, int cap1,
                                               const unsigned* __restrict__ stg2, const int* __restrict__ bc2, int cap2,
                                               const float* __restrict__ d1, const float* __restrict__ d2,
                                               const unsigned short* __restrict__ p,
                                               const unsigned short* __restrict__ q,
                                               const float* __restrict__ t0, float* __restrict__ out,
                                               int n) {
  __shared__ float accA[64 * 17];    // stride 17: odd -> bank spread by ro
  __shared__ float accB[64 * 17];
  int b = blockIdx.x, t = threadIdx.x;
  for (int i = t; i < 64 * 17; i += 256) { accA[i] = 0.f; accB[i] = 0.f; }
  __syncthreads();
  const int g = t >> 2, s = t & 3;

#pragma unroll 1
  for (int pass = 0; pass < 2; ++pass) {
    const unsigned* stg = pass ? stg2 : stg1;
    const int cap = pass ? cap2 : cap1;
    const int endc = pass ? bc2[b] : bc1[b];
    const unsigned short* src = pass ? q : p;
    float* acc = pass ? accB : accA;
    int start = b * cap;
    int cnt = min(endc, start + cap) - start;
    int i = g * 4;
    for (; i + 4 <= cnt; i += 256) {
      uint4 w = *(const uint4*)(stg + start + i);
      unsigned ws[4] = {w.x, w.y, w.z, w.w};
      uint2 v[4];
#pragma unroll
      for (int j = 0; j < 4; ++j)
        v[j] = *(const uint2*)(src + (size_t)(ws[j] & 0x1FFFFu) * 16 + s * 4);
#pragma unroll
      for (int j = 0; j < 4; ++j) {
        float* a = &acc[(ws[j] >> 17) * 17 + s * 4];
        atomicAdd(&a[0], bflo(v[j].x)); atomicAdd(&a[1], bfhi(v[j].x));
        atomicAdd(&a[2], bflo(v[j].y)); atomicAdd(&a[3], bfhi(v[j].y));
      }
    }
    for (int jj = i; jj < cnt; ++jj) {
      unsigned w = stg[start + jj];
      uint2 v = *(const uint2*)(src + (size_t)(w & 0x1FFFFu) * 16 + s * 4);
      float* a = &acc[(w >> 17) * 17 + s * 4];
      atomicAdd(&a[0], bflo(v.x)); atomicAdd(&a[1], bfhi(v.x));
      atomicAdd(&a[2], bflo(v.y)); atomicAdd(&a[3], bfhi(v.y));
    }
  }
  __syncthreads();

  int row_g = b * 64 + g;
  if (row_g < n) {
    float s1 = d1[row_g], s2 = d2[row_g];
    float4 t0v = *(const float4*)(t0 + (size_t)row_g * 16 + s * 4);
    float z[4];
    z[0] = t0v.x + s1 * accA[g * 17 + s * 4 + 0] + s2 * accB[g * 17 + s * 4 + 0];
    z[1] = t0v.y + s1 * accA[g * 17 + s * 4 + 1] + s2 * accB[g * 17 + s * 4 + 1];
    z[2] = t0v.z + s1 * accA[g * 17 + s * 4 + 2] + s2 * accB[g * 17 + s * 4 + 2];
    z[3] = t0v.w + s1 * accA[g * 17 + s * 4 + 3] + s2 * accB[g * 17 + s * 4 + 3];
    float m = fmaxf(fmaxf(z[0], z[1]), fmaxf(z[2], z[3]));
    m = fmaxf(m, __shfl_xor(m, 1));
    m = fmaxf(m, __shfl_xor(m, 2));
    float sum = expf(z[0] - m) + expf(z[1] - m) + expf(z[2] - m) + expf(z[3] - m);
    sum += __shfl_xor(sum, 1);
    sum += __shfl_xor(sum, 2);
    float lg = m + logf(sum);
    float4 o;
    o.x = z[0] - lg; o.y = z[1] - lg; o.z = z[2] - lg; o.w = z[3] - lg;
    *(float4*)(out + (size_t)row_g * 16 + s * 4) = o;
  }
}

extern "C" void kernel_launch(void* const* d_in, const int* in_sizes, int n_in,
                              void* d_out, int out_size, void* d_ws, size_t ws_size,
                              hipStream_t stream) {
  const float* x   = (const float*)d_in[0];
  const int*   a1i = (const int*)d_in[1];
  const int*   a2i = (const int*)d_in[3];
  const float* we  = (const float*)d_in[5];
  const float* wcl = (const float*)d_in[6];
  float* out = (float*)d_out;

  const int n  = in_sizes[0] / NFEAT;
  const int e1 = in_sizes[2];
  const int e2 = in_sizes[4];
  const int nb = (n + 63) / 64;     // <= 2048 (requires n <= 131072)

  // fixed bucket capacity: mean + 8*sigma + 64, rounded to 4 (uint4-aligned)
  auto capf = [](int e, int nbk) {
    int avg = (e + nbk - 1) / nbk;
    int c = avg + 8 * (int)sqrt((double)avg) + 64;
    return (c + 3) & ~3;
  };
  const int cap1 = capf(e1, nb);
  const int cap2 = capf(e2, nb);

  char* ws = (char*)d_ws;
  size_t off = 0;
  auto alloc = [&](size_t bytes) -> void* {
    void* p = ws + off;
    off += (bytes + 255) & ~(size_t)255;
    return p;
  };
  float* t0 = (float*)alloc((size_t)n * 16 * 4);
  float* t1 = (float*)alloc((size_t)n * 16 * 4);
  float* t2 = (float*)alloc((size_t)n * 16 * 4);
  unsigned short* U1 = (unsigned short*)alloc((size_t)n * 32 * 2);   // bf16
  unsigned short* U2 = (unsigned short*)alloc((size_t)n * 32 * 2);   // bf16
  unsigned short* pp = (unsigned short*)alloc((size_t)n * 16 * 2);   // bf16
  unsigned short* qq = (unsigned short*)alloc((size_t)n * 16 * 2);   // bf16
  float* d1 = (float*)alloc((size_t)n * 4);
  float* d2 = (float*)alloc((size_t)n * 4);
  unsigned* stg1 = (unsigned*)alloc((size_t)nb * cap1 * 4);
  unsigned* stg2 = (unsigned*)alloc((size_t)nb * cap2 * 4);
  int* bc1 = (int*)alloc((size_t)nb * 4);
  int* bc2 = (int*)alloc((size_t)nb * 4);

  (void)ws_size; (void)n_in; (void)out_size;

  k_bcinit<<<(nb + 255) / 256, 256, 0, stream>>>(bc1, bc2, nb, cap1, cap2);

  k_bin<<<(e1 + EB - 1) / EB, 256, 0, stream>>>(a1i, a1i + e1, bc1, stg1, e1, nb, cap1);
  k_bin<<<(e2 + EB - 1) / EB, 256, 0, stream>>>(a2i, a2i + e2, bc2, stg2, e2, nb, cap2);

  k_deg<<<nb, 256, 0, stream>>>(stg1, bc1, cap1, d1, n);
  k_deg<<<nb, 256, 0, stream>>>(stg2, bc2, cap2, d2, n);

  k_embed<<<(n + 63) / 64, 256, 0, stream>>>(x, we, wcl, d1, d2, t0, U1, U2, n);

  k_inner<<<nb, 256, 0, stream>>>(stg1, bc1, cap1, stg2, bc2, cap2,
                                  d1, d2, U1, U2, t1, t2, pp, qq, n);

  k_outer<<<nb, 256, 0, stream>>>(stg1, bc1, cap1, stg2, bc2, cap2,
                                  d1, d2, pp, qq, t0, out, n);
}